// Round 3
// baseline (203.423 us; speedup 1.0000x reference)
//
#include <hip/hip_runtime.h>
#include <math.h>

#define NB 8
#define NA 256
#define NBD 256
#define NC 64
#define NF 129

struct alignas(8) cpx { float re, im; };

__device__ __forceinline__ cpx cmul(cpx a, cpx b){
  cpx r;
  r.re = fmaf(a.re, b.re, -(a.im * b.im));
  r.im = fmaf(a.re, b.im,  a.im * b.re);
  return r;
}

// LDS tile: 256 rows (n) x 32 complex columns (g), additive swizzle to avoid
// bank conflicts in BOTH the stride-16 and consecutive-16 FFT phases.
__device__ __forceinline__ int PHY(int n, int g){
  return (n << 5) | ((g + n + (n >> 4)) & 31);
}

// Twiddle table init: tw[k] = (cos(2*pi*k/256), sin(2*pi*k/256)), computed in
// double and rounded to fp32 (0.5 ulp).
__global__ void k0_twiddle(float2* __restrict__ tw){
  int k = threadIdx.x;
  double ang = 6.283185307179586476925286766559 * (double)k / 256.0;
  tw[k] = make_float2((float)cos(ang), (float)sin(ang));
}

// In-register 16-point FFT, SIGN=-1 forward / +1 inverse (unnormalized).
template<int SIGN>
__device__ __forceinline__ void fft16(cpx a[16]){
  cpx tmp;
  #define SW(i,j) tmp = a[i]; a[i] = a[j]; a[j] = tmp;
  SW(1,8) SW(2,4) SW(3,12) SW(5,10) SW(7,14) SW(11,13)
  #undef SW
  const float CT[8] = {1.f, 0.92387953251128674f, 0.70710678118654752f, 0.38268343236508977f,
                       0.f, -0.38268343236508977f, -0.70710678118654752f, -0.92387953251128674f};
  const float ST[8] = {0.f, 0.38268343236508977f, 0.70710678118654752f, 0.92387953251128674f,
                       1.f, 0.92387953251128674f, 0.70710678118654752f, 0.38268343236508977f};
  #pragma unroll
  for (int s = 1; s <= 4; ++s){
    const int m = 1 << s, half = m >> 1, str = 16 >> s;
    #pragma unroll
    for (int k = 0; k < 16; k += m){
      #pragma unroll
      for (int j = 0; j < half; ++j){
        cpx w; w.re = CT[j*str]; w.im = (float)SIGN * ST[j*str];
        cpx t = cmul(a[k+j+half], w);
        cpx u = a[k+j];
        a[k+j].re      = u.re + t.re; a[k+j].im      = u.im + t.im;
        a[k+j+half].re = u.re - t.re; a[k+j+half].im = u.im - t.im;
      }
    }
  }
}

// 256-point FFT on LDS column g, 16 threads (t = 0..15) cooperate.
// Caller must __syncthreads() after populating the tile. Ends synced.
template<int SIGN>
__device__ __forceinline__ void fft256_col(cpx* __restrict__ tile, int g, int t,
                                           const float2* __restrict__ tw){
  // Phase A: DFT-16 over n1 (stride 16), twiddle, in-place (thread-private set)
  cpx a[16];
  #pragma unroll
  for (int n1 = 0; n1 < 16; ++n1) a[n1] = tile[PHY(16*n1 + t, g)];
  fft16<SIGN>(a);
  #pragma unroll
  for (int k1 = 1; k1 < 16; ++k1){
    float2 tv = tw[(t * k1) & 255];
    cpx w; w.re = tv.x; w.im = (SIGN < 0) ? -tv.y : tv.y;
    a[k1] = cmul(a[k1], w);
  }
  #pragma unroll
  for (int k1 = 0; k1 < 16; ++k1) tile[PHY(16*k1 + t, g)] = a[k1];
  __syncthreads();

  // Phase B: DFT-16 over n2 (consecutive 16), results to natural order
  cpx b[16];
  #pragma unroll
  for (int n2 = 0; n2 < 16; ++n2) b[n2] = tile[PHY(16*t + n2, g)];
  fft16<SIGN>(b);
  __syncthreads();   // all reads done before cross-thread writes
  #pragma unroll
  for (int k2 = 0; k2 < 16; ++k2) tile[PHY(t + 16*k2, g)] = b[k2];
  __syncthreads();
}

// K1: rfft along b for each (batch, a) row-tile. Packs channel pairs (2g,2g+1)
// as complex. Writes mid[b][f][a][c] as float4 = (A.re,A.im,B.re,B.im).
__global__ __launch_bounds__(512) void k1_rfft_b(const float* __restrict__ x,
                                                 float4* __restrict__ mid4,
                                                 const float2* __restrict__ tw){
  __shared__ cpx tile[256*32];
  const int tid = threadIdx.x;
  const int blk = blockIdx.x;            // bb*256 + a
  const int bb = blk >> 8, a = blk & 255;
  const int g = tid >> 4, t = tid & 15;

  const float4* src = (const float4*)(x + (size_t)blk * (NBD * NC));
  #pragma unroll
  for (int it = 0; it < 8; ++it){
    int idx = it*512 + tid;          // float4 index into [256][16]
    int j = idx >> 4, q = idx & 15;
    float4 v = src[idx];
    cpx p0; p0.re = v.x; p0.im = v.y;
    cpx p1; p1.re = v.z; p1.im = v.w;
    tile[PHY(j, 2*q)]   = p0;
    tile[PHY(j, 2*q+1)] = p1;
  }
  __syncthreads();

  fft256_col<-1>(tile, g, t, tw);

  // unpack packed spectrum -> per-channel A,B; store f = 0..128
  for (int it = 0; it < 9; ++it){
    int idx = it*512 + tid;
    if (idx < NF*32){
      int k = idx >> 5, gg = idx & 31;
      cpx zk = tile[PHY(k, gg)];
      cpx zm = tile[PHY((256 - k) & 255, gg)];
      float4 o;
      o.x = 0.5f*(zk.re + zm.re);   // A.re
      o.y = 0.5f*(zk.im - zm.im);   // A.im
      o.z = 0.5f*(zk.im + zm.im);   // B.re
      o.w = 0.5f*(zm.re - zk.re);   // B.im
      mid4[(((size_t)bb*NF + k)*256 + a)*32 + gg] = o;
    }
  }
}

// K2: for each (batch, f, c-half): FFT along a, multiply by W[ka,f,c]/65536,
// inverse FFT along a, in place in mid.
__global__ __launch_bounds__(512) void k2_fft_a_mul(float2* __restrict__ mid2,
                                                    const float* __restrict__ wre,
                                                    const float* __restrict__ wim,
                                                    const float2* __restrict__ tw){
  __shared__ cpx tile[256*32];
  const int tid = threadIdx.x;
  int blk = blockIdx.x;                  // ((bb*129 + f)*2 + h)
  const int h = blk & 1; blk >>= 1;
  const int f = blk % NF, bb = blk / NF;
  const int g = tid >> 4, t = tid & 15;
  const int c0 = h * 32;

  float2* base = mid2 + ((size_t)bb*NF + f) * (256*64) + c0;
  #pragma unroll
  for (int it = 0; it < 16; ++it){
    int idx = it*512 + tid;
    int a = idx >> 5, gc = idx & 31;
    float2 v = base[(size_t)a*64 + gc];
    cpx z; z.re = v.x; z.im = v.y;
    tile[PHY(a, gc)] = z;
  }
  __syncthreads();

  fft256_col<-1>(tile, g, t, tw);

  #pragma unroll
  for (int it = 0; it < 16; ++it){
    int idx = it*512 + tid;
    int ka = idx >> 5, gc = idx & 31;
    size_t wi = ((size_t)ka*NF + f)*64 + (c0 + gc);
    cpx w; w.re = wre[wi] * (1.0f/65536.0f); w.im = wim[wi] * (1.0f/65536.0f);
    cpx v = tile[PHY(ka, gc)];
    tile[PHY(ka, gc)] = cmul(v, w);
  }
  __syncthreads();

  fft256_col<+1>(tile, g, t, tw);

  #pragma unroll
  for (int it = 0; it < 16; ++it){
    int idx = it*512 + tid;
    int a = idx >> 5, gc = idx & 31;
    cpx v = tile[PHY(a, gc)];
    float2 o; o.x = v.re; o.y = v.im;
    base[(size_t)a*64 + gc] = o;
  }
}

// K3: irfft along b for each (batch, a): Hermitian-extend packed channel-pair
// spectrum S = A + iB, inverse complex FFT, Re->even channel, Im->odd channel.
// c2r semantics: the imaginary parts of the DC (f=0) and Nyquist (f=128) bins
// are IGNORED by irfft — drop them here or they leak across channel pairs.
__global__ __launch_bounds__(512) void k3_irfft_b(const float4* __restrict__ mid4,
                                                  float2* __restrict__ y2,
                                                  const float2* __restrict__ tw){
  __shared__ cpx tile[256*32];
  const int tid = threadIdx.x;
  const int blk = blockIdx.x;            // bb*256 + a
  const int bb = blk >> 8, a = blk & 255;
  const int g = tid >> 4, t = tid & 15;

  for (int it = 0; it < 9; ++it){
    int idx = it*512 + tid;
    if (idx < NF*32){
      int f = idx >> 5, gg = idx & 31;
      float4 v = mid4[(((size_t)bb*NF + f)*256 + a)*32 + gg];
      cpx sd;
      if (f == 0 || f == 128){
        sd.re = v.x;                 // Re(A); Im(A) dropped (c2r ignores it)
        sd.im = v.z;                 // Re(B); Im(B) dropped
      } else {
        sd.re = v.x - v.w; sd.im = v.y + v.z;   // S[f] = A + iB
      }
      tile[PHY(f, gg)] = sd;
      if (f >= 1 && f <= 127){
        cpx se; se.re = v.x + v.w; se.im = v.z - v.y;   // S[256-f] = conj(A)+i*conj(B)
        tile[PHY(256 - f, gg)] = se;
      }
    }
  }
  __syncthreads();

  fft256_col<+1>(tile, g, t, tw);

  float2* dst = y2 + (size_t)blk * (256*32);
  #pragma unroll
  for (int it = 0; it < 16; ++it){
    int idx = it*512 + tid;
    int n = idx >> 5, gg = idx & 31;
    cpx v = tile[PHY(n, gg)];
    float2 o; o.x = v.re; o.y = v.im;
    dst[(size_t)n*32 + gg] = o;
  }
}

extern "C" void kernel_launch(void* const* d_in, const int* in_sizes, int n_in,
                              void* d_out, int out_size, void* d_ws, size_t ws_size,
                              hipStream_t stream){
  const float* x   = (const float*)d_in[0];
  const float* wre = (const float*)d_in[1];
  const float* wim = (const float*)d_in[2];

  float2* tw = (float2*)d_ws;                    // 256 float2 = 2 KB
  float*  mid = (float*)d_ws + 512;              // NB*NF*256*64 complex = ~135.3 MB

  k0_twiddle  <<<1,   256, 0, stream>>>(tw);
  k1_rfft_b   <<<NB*NA,    512, 0, stream>>>(x, (float4*)mid, tw);
  k2_fft_a_mul<<<NB*NF*2,  512, 0, stream>>>((float2*)mid, wre, wim, tw);
  k3_irfft_b  <<<NB*NA,    512, 0, stream>>>((const float4*)mid, (float2*)d_out, tw);
}